// Round 3
// baseline (1767.625 us; speedup 1.0000x reference)
//
#include <hip/hip_runtime.h>
#include <stdint.h>

// Problem constants (fixed by setup_inputs): B=16, N=2048, D=768
#define BB 16
#define NN 2048
#define DD 768
#define BN (BB*NN)          // 32768 rows per tensor
#define NCH (DD/32)         // 24 K-chunks of 32

// ---------------------------------------------------------------------------
// Memory plan:
//  ws (floats):
//   [0,      131072)  pmax  [b][ms(4)][n]
//   [131072, 262144)  pidx  (int)
//   [262144, 294912)  rm    final reuse_map copy for blend
//   [294912, 327680)  fidx  (int) final argmax          -> 1.25 MB total
//  d_out doubles as scratch: out_ri region holds qh|ql (bf16 hi/lo of
//  normalized query_input), out_rv region holds ch|cl — both are dead
//  until blend_kernel overwrites them at the very end.
//
// bf16x3 trick: x = hi + lo (both bf16, RNE). dot(nq,nc) = hh + lh + hl
// (+ ll dropped, |err| <= sum|a*b| * 2^-18 ~ 5e-6 on a cosine score).
//
// ROUND-3 CHANGES (theory: kernel is memory-system-bound, MfmaUtil 12%):
//  * XCD-locality remap: 1D grid, decoded so the 16 n-tile blocks sharing
//    one (b,ms) B-panel set all have id%8 == same XCD -> B re-reads become
//    L2 hits instead of 5x HBM over-fetch (FETCH was 1.06 GB vs 201 MB
//    compulsory).
//  * Occupancy 2->4 blocks/CU: single-buffered LDS (34 KB) with T14 split
//    (issue next-chunk loads early, MFMA, barrier, ds_write, barrier).
// ---------------------------------------------------------------------------

typedef __attribute__((ext_vector_type(8))) short bf16x8;   // 4 VGPRs
typedef __attribute__((ext_vector_type(4))) float f32x4;    // 4 VGPRs

__device__ __forceinline__ ushort f2bf_rne(float x) {
    uint32_t u = __float_as_uint(x);
    u += 0x7fffu + ((u >> 16) & 1u);
    return (ushort)(u >> 16);
}

// --- Kernel 1: per-row L2 norm + normalized bf16 hi/lo split ---------------
// one wave per row; rows [0,BN)=q, [BN,2BN)=c.
__global__ __launch_bounds__(256) void normconv_kernel(
        const float* __restrict__ qi, const float* __restrict__ ci,
        ushort* __restrict__ qh, ushort* __restrict__ ql,
        ushort* __restrict__ ch, ushort* __restrict__ cl) {
    int row  = blockIdx.x * 4 + (threadIdx.x >> 6);
    int lane = threadIdx.x & 63;
    bool isq = row < BN;
    const float* src = isq ? qi : ci;
    int r = row & (BN - 1);
    const float4* p = (const float4*)(src + (size_t)r * DD);
    float4 v[3];
    float s = 0.0f;
#pragma unroll
    for (int k = 0; k < 3; k++) {
        v[k] = p[lane + 64 * k];
        s += v[k].x*v[k].x + v[k].y*v[k].y + v[k].z*v[k].z + v[k].w*v[k].w;
    }
#pragma unroll
    for (int off = 32; off; off >>= 1) s += __shfl_xor(s, off);
    float inv = 1.0f / sqrtf(s);
    ushort* dh = (isq ? qh : ch) + (size_t)r * DD;
    ushort* dl = (isq ? ql : cl) + (size_t)r * DD;
#pragma unroll
    for (int k = 0; k < 3; k++) {
        int f = lane + 64 * k;
        float n[4] = {v[k].x * inv, v[k].y * inv, v[k].z * inv, v[k].w * inv};
        ushort hs[4], ls[4];
#pragma unroll
        for (int e = 0; e < 4; e++) {
            hs[e] = f2bf_rne(n[e]);
            ls[e] = f2bf_rne(n[e] - __uint_as_float((uint32_t)hs[e] << 16));
        }
        uint2 hv, lv;
        hv.x = (uint32_t)hs[0] | ((uint32_t)hs[1] << 16);
        hv.y = (uint32_t)hs[2] | ((uint32_t)hs[3] << 16);
        lv.x = (uint32_t)ls[0] | ((uint32_t)ls[1] << 16);
        lv.y = (uint32_t)ls[2] | ((uint32_t)ls[3] << 16);
        *(uint2*)(dh + 4 * (size_t)f) = hv;
        *(uint2*)(dl + 4 * (size_t)f) = lv;
    }
}

// --- Kernel 2: MFMA GEMM (bf16x3) + running max/argmax over M --------------
// 1D grid of 1024 blocks, XCD-remapped (see decode below), 4 blocks/CU
// (34 KB LDS, <=128 VGPR). 128x128 tile, 4 waves as 2x2, each wave 64x64
// via 4x4 16x16x32 frags. K chunked by 32, SINGLE-buffered LDS, T14 split:
// next-chunk global loads issued before MFMA; ds_writes between the two
// barriers.
// LDS slot-XOR swizzle: physical 16B slot = logical ^ ((row>>1)&3) on both
// write and read -> <=2-way bank aliasing on frag reads (free, m136).
// MFMA layouts (m89/m92-verified): A/B frag: row lane&15, k=(lane>>4)*8+e
// (8 contiguous); D: col(N of B)=lane&15, row(M of A)=(lane>>4)*4+reg.
__global__ __launch_bounds__(256, 4) void simmax_kernel(
        const ushort* __restrict__ qh, const ushort* __restrict__ ql,
        const ushort* __restrict__ ch, const ushort* __restrict__ cl,
        float* __restrict__ pmax, int* __restrict__ pidx) {
    __shared__ ushort smem[4][128 * 32];      // 32 KiB (single-buffered)
    __shared__ float  redm[2][128];           // cross-wx merge staging
    __shared__ int    redi[2][128];

    // --- XCD-locality decode: id%8 is the XCD (m09). Group G=(b,ms) spans
    // 16 n-tile blocks that read identical B-panels; place the whole group
    // on one XCD so the panel is fetched once into that XCD's L2.
    //   id = (G>>3)*128 + j*8 + (G&7),  j = n-tile index in [0,16)
    const int id  = blockIdx.x;
    const int xcd = id & 7;
    const int w_  = id >> 3;          // [0,128)
    const int j_  = w_ & 15;          // n-tile
    const int G   = (w_ >> 4) * 8 + xcd;   // [0,64) = b*4 + ms
    const int b   = G >> 2;
    const int ms  = G & 3;
    const int n0  = j_ * 128;

    const int t  = threadIdx.x;
    const int l  = t & 63, wid = t >> 6;
    const int wy = wid >> 1, wx = wid & 1;
    const int fr = l & 15,  fs = l >> 4;
    const int n0g = b * NN + n0;

    // staging coords: 2 passes x 256 threads cover 128 rows x 4 slots
    const int row0 = t >> 2,         sl0 = t & 3;
    const int row1 = (t + 256) >> 2, sl1 = t & 3;
    const int w0 = row0 * 32 + (sl0 ^ ((row0 >> 1) & 3)) * 8;  // swizzled write
    const int w1 = row1 * 32 + (sl1 ^ ((row1 >> 1) & 3)) * 8;
    // fragment read offsets: row bits 1..2 come only from fr
    const int swz = (fs ^ ((fr >> 1) & 3)) * 8;
    const int ra0 = (wy * 64 + fr) * 32 + swz;
    const int rb0 = (wx * 64 + fr) * 32 + swz;

    const ushort* srcs[4] = {qh, ql, ch, cl};

    float rmax[16]; int ridx[16];
#pragma unroll
    for (int k = 0; k < 16; k++) { rmax[k] = -3.0e38f; ridx[k] = 0; }

    uint4 stg[8];

    for (int mt = ms; mt < 16; mt += 4) {      // ascending -> first-tie wins
        const int m0  = mt * 128;
        const int m0g = b * NN + m0;

        f32x4 acc[4][4];
#pragma unroll
        for (int i = 0; i < 4; i++)
#pragma unroll
            for (int j = 0; j < 4; j++)
#pragma unroll
                for (int r = 0; r < 4; r++) acc[i][j][r] = 0.0f;

        // prologue: stage chunk 0 (previous m-tile's last barrier already
        // guaranteed all readers done with LDS)
#pragma unroll
        for (int a = 0; a < 4; a++) {
            const ushort* s = srcs[a] + (size_t)(a < 2 ? n0g : m0g) * DD;
            stg[a*2+0] = *(const uint4*)(s + (size_t)row0 * DD + sl0 * 8);
            stg[a*2+1] = *(const uint4*)(s + (size_t)row1 * DD + sl1 * 8);
        }
#pragma unroll
        for (int a = 0; a < 4; a++) {
            *(uint4*)&smem[a][w0] = stg[a*2+0];
            *(uint4*)&smem[a][w1] = stg[a*2+1];
        }
        __syncthreads();

        for (int c = 0; c < NCH; c++) {
            if (c + 1 < NCH) {                 // issue next-chunk loads early
                const int k1 = (c + 1) * 32;
#pragma unroll
                for (int a = 0; a < 4; a++) {
                    const ushort* s = srcs[a] + (size_t)(a < 2 ? n0g : m0g) * DD + k1;
                    stg[a*2+0] = *(const uint4*)(s + (size_t)row0 * DD + sl0 * 8);
                    stg[a*2+1] = *(const uint4*)(s + (size_t)row1 * DD + sl1 * 8);
                }
            }
            bf16x8 ah[4], al[4], bhf[4], blf[4];
#pragma unroll
            for (int i = 0; i < 4; i++) {
                ah[i]  = *(const bf16x8*)&smem[0][ra0 + i * 512];
                al[i]  = *(const bf16x8*)&smem[1][ra0 + i * 512];
                bhf[i] = *(const bf16x8*)&smem[2][rb0 + i * 512];
                blf[i] = *(const bf16x8*)&smem[3][rb0 + i * 512];
            }
#pragma unroll
            for (int i = 0; i < 4; i++)
#pragma unroll
                for (int j = 0; j < 4; j++) {
                    asm("v_mfma_f32_16x16x32_bf16 %0, %1, %2, %0"
                        : "+v"(acc[i][j]) : "v"(ah[i]), "v"(bhf[j]));
                    asm("v_mfma_f32_16x16x32_bf16 %0, %1, %2, %0"
                        : "+v"(acc[i][j]) : "v"(al[i]), "v"(bhf[j]));
                    asm("v_mfma_f32_16x16x32_bf16 %0, %1, %2, %0"
                        : "+v"(acc[i][j]) : "v"(ah[i]), "v"(blf[j]));
                }
            __syncthreads();                   // all reads of chunk c done
            if (c + 1 < NCH) {
#pragma unroll
                for (int a = 0; a < 4; a++) {
                    *(uint4*)&smem[a][w0] = stg[a*2+0];
                    *(uint4*)&smem[a][w1] = stg[a*2+1];
                }
                __syncthreads();               // chunk c+1 visible
            }
        }

        // fold this m-tile into running (max, argmax); j ascending + strict >
        // preserves first-occurrence ties (cols ascend with mt and j)
#pragma unroll
        for (int j = 0; j < 4; j++) {
            const int col = m0 + wx * 64 + j * 16 + fr;
#pragma unroll
            for (int i = 0; i < 4; i++)
#pragma unroll
                for (int r = 0; r < 4; r++) {
                    float val = acc[i][j][r];
                    int k = i * 4 + r;
                    if (val > rmax[k]) { rmax[k] = val; ridx[k] = col; }
                }
        }
    }

    // cross-lane reduce over fr (16 lanes share a row set), index tie-break;
    // stage per-wave result in LDS — waves wx=0/1 hold different col halves
    // of the SAME rows and must be merged.
#pragma unroll
    for (int k = 0; k < 16; k++) {
        float m = rmax[k]; int id2 = ridx[k];
#pragma unroll
        for (int off = 1; off < 16; off <<= 1) {
            float om = __shfl_xor(m, off);
            int   oi = __shfl_xor(id2, off);
            if (om > m || (om == m && oi < id2)) { m = om; id2 = oi; }
        }
        if (fr == 0) {
            int r_loc = wy * 64 + (k >> 2) * 16 + fs * 4 + (k & 3);
            redm[wx][r_loc] = m;
            redi[wx][r_loc] = id2;
        }
    }
    __syncthreads();
    if (t < 128) {
        float m0v = redm[0][t]; int i0 = redi[0][t];
        float m1v = redm[1][t]; int i1 = redi[1][t];
        // wx=0 holds lower columns: on exact tie keep smaller index
        if (m1v > m0v || (m1v == m0v && i1 < i0)) { m0v = m1v; i0 = i1; }
        pmax[(b * 4 + ms) * NN + n0 + t] = m0v;
        pidx[(b * 4 + ms) * NN + n0 + t] = i0;
    }
}

// --- Kernel 3: merge 4 m-split partials + sigmoid threshold ----------------
__global__ __launch_bounds__(256) void merge_kernel(
        const float* __restrict__ pmax, const int* __restrict__ pidx,
        const float* __restrict__ st,
        float* __restrict__ out_map,
        float* __restrict__ ws_rm, int* __restrict__ ws_idx) {
    int id = blockIdx.x * 256 + threadIdx.x;   // [0, BN)
    int b = id >> 11, n = id & 2047;
    float best = pmax[(b * 4) * NN + n];
    int   bi   = pidx[(b * 4) * NN + n];
#pragma unroll
    for (int s = 1; s < 4; s++) {
        float p = pmax[(b * 4 + s) * NN + n];
        int   q = pidx[(b * 4 + s) * NN + n];
        if (p > best || (p == best && q < bi)) { best = p; bi = q; }
    }
    float thr = 1.0f / (1.0f + expf(-st[n]));
    float rm  = 1.0f / (1.0f + expf(-40.0f * (best - thr)));
    out_map[id] = rm;
    ws_rm[id]   = rm;
    ws_idx[id]  = bi;
}

// --- Kernel 4: gather + blend, f32 stores (overwrites the bf16 scratch) ----
__global__ __launch_bounds__(256) void blend_kernel(
        const float* __restrict__ qi, const float* __restrict__ qv,
        const float* __restrict__ ci, const float* __restrict__ cv,
        const float* __restrict__ ws_rm, const int* __restrict__ ws_idx,
        float* __restrict__ out_ri, float* __restrict__ out_rv) {
    int row  = blockIdx.x * 4 + (threadIdx.x >> 6);
    int lane = threadIdx.x & 63;
    float rm  = ws_rm[row];
    int gidx  = ws_idx[row];
    int b     = row >> 11;
    float om  = 1.0f - rm;
    const float4* q4 = (const float4*)(qi + (size_t)row * DD);
    const float4* v4 = (const float4*)(qv + (size_t)row * DD);
    const float4* s4 = (const float4*)(ci + ((size_t)b * NN + gidx) * DD);
    const float4* w4 = (const float4*)(cv + ((size_t)b * NN + gidx) * DD);
    float4* ori = (float4*)(out_ri + (size_t)row * DD);
    float4* orv = (float4*)(out_rv + (size_t)row * DD);
#pragma unroll
    for (int k = 0; k < 3; k++) {
        int f = lane + 64 * k;
        float4 a = q4[f], si = s4[f];
        float4 o;
        o.x = om * a.x + rm * si.x;
        o.y = om * a.y + rm * si.y;
        o.z = om * a.z + rm * si.z;
        o.w = om * a.w + rm * si.w;
        ori[f] = o;
        float4 av = v4[f], sv = w4[f];
        float4 p;
        p.x = om * av.x + rm * sv.x;
        p.y = om * av.y + rm * sv.y;
        p.z = om * av.z + rm * sv.z;
        p.w = om * av.w + rm * sv.w;
        orv[f] = p;
    }
}

extern "C" void kernel_launch(void* const* d_in, const int* in_sizes, int n_in,
                              void* d_out, int out_size, void* d_ws, size_t ws_size,
                              hipStream_t stream) {
    const float* qi = (const float*)d_in[0];
    const float* qv = (const float*)d_in[1];
    const float* ci = (const float*)d_in[2];
    const float* cv = (const float*)d_in[3];
    const float* st = (const float*)d_in[4];

    float* ws    = (float*)d_ws;
    float* pmax  = ws;
    int*   pidx  = (int*)(ws + 131072);
    float* ws_rm = ws + 262144;
    int*   ws_id = (int*)(ws + 294912);

    float* out     = (float*)d_out;
    float* out_map = out;                                  // [B,N]
    float* out_ri  = out + 32768;                          // [B,N,D]
    float* out_rv  = out + 32768 + (size_t)BN * DD;        // [B,N,D]

    // bf16 hi/lo scratch aliases the (not-yet-written) big outputs
    ushort* qh = (ushort*)out_ri;
    ushort* ql = qh + (size_t)BN * DD;
    ushort* ch = (ushort*)out_rv;
    ushort* cl = ch + (size_t)BN * DD;

    normconv_kernel<<<(2 * BN) / 4, 256, 0, stream>>>(qi, ci, qh, ql, ch, cl);
    simmax_kernel<<<1024, 256, 0, stream>>>(qh, ql, ch, cl, pmax, pidx);
    merge_kernel<<<BN / 256, 256, 0, stream>>>(pmax, pidx, st,
                                               out_map, ws_rm, ws_id);
    blend_kernel<<<BN / 4, 256, 0, stream>>>(qi, qv, ci, cv, ws_rm, ws_id,
                                             out_ri, out_rv);
}

// Round 4
// 798.131 us; speedup vs baseline: 2.2147x; 2.2147x over previous
//
#include <hip/hip_runtime.h>
#include <stdint.h>

// Problem constants (fixed by setup_inputs): B=16, N=2048, D=768
#define BB 16
#define NN 2048
#define DD 768
#define BN (BB*NN)          // 32768 rows per tensor
#define NCH (DD/32)         // 24 K-chunks of 32

// ---------------------------------------------------------------------------
// Memory plan:
//  ws (floats):
//   [0,      131072)  pmax  [b][ms(4)][n]
//   [131072, 262144)  pidx  (int)
//   [262144, 294912)  rm    final reuse_map copy for blend
//   [294912, 327680)  fidx  (int) final argmax          -> 1.25 MB total
//  d_out doubles as scratch: out_ri region holds qh|ql (bf16 hi/lo of
//  normalized query_input), out_rv region holds ch|cl — both are dead
//  until blend_kernel overwrites them at the very end.
//
// bf16x3 trick: x = hi + lo (both bf16, RNE). dot(nq,nc) = hh + lh + hl
// (+ ll dropped, |err| <= sum|a*b| * 2^-18 ~ 5e-6 on a cosine score).
//
// ROUND-4 CHANGES:
//  * REVERT round-3 XCD remap (doubled FETCH: 8 groups x ~9MB streaming
//    sets thrashed each 4MB XCD L2) and single-buffer -> back to round-2
//    3D grid + double buffer.
//  * Staging via __builtin_amdgcn_global_load_lds width=16 (m151: +35% over
//    reg-staging at 128^2 tiles): LDS dest is lane-linear (m104); the
//    conflict-free XOR swizzle is preserved by PRE-SWIZZLING the global
//    source slot per lane (m173): lane l fetches global 16B-slot
//    (l&3)^((l>>3)&3) so read-side swizzle is unchanged (0 conflicts).
// ---------------------------------------------------------------------------

typedef __attribute__((ext_vector_type(8))) short bf16x8;   // 4 VGPRs
typedef __attribute__((ext_vector_type(4))) float f32x4;    // 4 VGPRs

__device__ __forceinline__ ushort f2bf_rne(float x) {
    uint32_t u = __float_as_uint(x);
    u += 0x7fffu + ((u >> 16) & 1u);
    return (ushort)(u >> 16);
}

__device__ __forceinline__ void gload16(const void* g, void* l) {
    __builtin_amdgcn_global_load_lds(
        (const __attribute__((address_space(1))) void*)g,
        (__attribute__((address_space(3))) void*)l,
        16, 0, 0);
}

// --- Kernel 1: per-row L2 norm + normalized bf16 hi/lo split ---------------
// one wave per row; rows [0,BN)=q, [BN,2BN)=c.
__global__ __launch_bounds__(256) void normconv_kernel(
        const float* __restrict__ qi, const float* __restrict__ ci,
        ushort* __restrict__ qh, ushort* __restrict__ ql,
        ushort* __restrict__ ch, ushort* __restrict__ cl) {
    int row  = blockIdx.x * 4 + (threadIdx.x >> 6);
    int lane = threadIdx.x & 63;
    bool isq = row < BN;
    const float* src = isq ? qi : ci;
    int r = row & (BN - 1);
    const float4* p = (const float4*)(src + (size_t)r * DD);
    float4 v[3];
    float s = 0.0f;
#pragma unroll
    for (int k = 0; k < 3; k++) {
        v[k] = p[lane + 64 * k];
        s += v[k].x*v[k].x + v[k].y*v[k].y + v[k].z*v[k].z + v[k].w*v[k].w;
    }
#pragma unroll
    for (int off = 32; off; off >>= 1) s += __shfl_xor(s, off);
    float inv = 1.0f / sqrtf(s);
    ushort* dh = (isq ? qh : ch) + (size_t)r * DD;
    ushort* dl = (isq ? ql : cl) + (size_t)r * DD;
#pragma unroll
    for (int k = 0; k < 3; k++) {
        int f = lane + 64 * k;
        float n[4] = {v[k].x * inv, v[k].y * inv, v[k].z * inv, v[k].w * inv};
        ushort hs[4], ls[4];
#pragma unroll
        for (int e = 0; e < 4; e++) {
            hs[e] = f2bf_rne(n[e]);
            ls[e] = f2bf_rne(n[e] - __uint_as_float((uint32_t)hs[e] << 16));
        }
        uint2 hv, lv;
        hv.x = (uint32_t)hs[0] | ((uint32_t)hs[1] << 16);
        hv.y = (uint32_t)hs[2] | ((uint32_t)hs[3] << 16);
        lv.x = (uint32_t)ls[0] | ((uint32_t)ls[1] << 16);
        lv.y = (uint32_t)ls[2] | ((uint32_t)ls[3] << 16);
        *(uint2*)(dh + 4 * (size_t)f) = hv;
        *(uint2*)(dl + 4 * (size_t)f) = lv;
    }
}

// --- Kernel 2: MFMA GEMM (bf16x3) + running max/argmax over M --------------
// grid (ntile=16, msplit=4, b=16) = 1024 blocks, 2/CU (~66KB LDS).
// 128x128 tile, 4 waves as 2x2, each wave 64x64 via 4x4 16x16x32 frags.
// K chunked by 32, double-buffered LDS via global_load_lds dwordx4; chunk
// c+1's loads issued before chunk c's MFMA; one barrier per chunk.
// LDS layout: [buf][arr][128 rows][4 slots of 8 ushorts]; phys slot p of
// row r holds global slot p ^ ((r>>1)&3) (involution). Staged by fetching
// pre-swizzled global addresses with lane-linear LDS dest.
// MFMA layouts (m89/m92-verified): A/B frag: row lane&15, k=(lane>>4)*8+e
// (8 contiguous); D: col(N of B)=lane&15, row(M of A)=(lane>>4)*4+reg.
__global__ __launch_bounds__(256, 2) void simmax_kernel(
        const ushort* __restrict__ qh, const ushort* __restrict__ ql,
        const ushort* __restrict__ ch, const ushort* __restrict__ cl,
        float* __restrict__ pmax, int* __restrict__ pidx) {
    __shared__ ushort smem[2][4][128 * 32];   // 64 KiB
    __shared__ float  redm[2][128];           // cross-wx merge staging
    __shared__ int    redi[2][128];

    const int t  = threadIdx.x;
    const int l  = t & 63, wid = t >> 6;
    const int wy = wid >> 1, wx = wid & 1;
    const int fr = l & 15,  fs = l >> 4;
    const int n0 = blockIdx.x * 128;
    const int ms = blockIdx.y;
    const int b  = blockIdx.z;
    const int n0g = b * NN + n0;

    // staging constants: wave wid stages rows [wid*32, wid*32+32) of each
    // array in 2 issues of 16 rows; lane l -> row rb+u*16+(l>>2), LDS phys
    // slot l&3, global slot gs=(l&3)^((l>>3)&3)  (== (l&3)^((row>>1)&3))
    const int rowl = l >> 2;
    const int gs   = (l & 3) ^ ((l >> 3) & 3);
    const int rb   = wid * 32;

    // fragment read offsets: phys slot = fs ^ ((fr>>1)&3)
    const int swz = (fs ^ ((fr >> 1) & 3)) * 8;
    const int ra0 = (wy * 64 + fr) * 32 + swz;
    const int rb0 = (wx * 64 + fr) * 32 + swz;

    const ushort* srcs[4] = {qh, ql, ch, cl};

    float rmax[16]; int ridx[16];
#pragma unroll
    for (int k = 0; k < 16; k++) { rmax[k] = -3.0e38f; ridx[k] = 0; }

    for (int mt = ms; mt < 16; mt += 4) {      // ascending -> first-tie wins
        const int m0  = mt * 128;
        const int m0g = b * NN + m0;

        f32x4 acc[4][4];
#pragma unroll
        for (int i = 0; i < 4; i++)
#pragma unroll
            for (int j = 0; j < 4; j++)
#pragma unroll
                for (int r = 0; r < 4; r++) acc[i][j][r] = 0.0f;

        // prologue: stage chunk 0 into buf 0 (last reader of buf0 was >=2
        // barriers ago)
#pragma unroll
        for (int a = 0; a < 4; a++) {
            const ushort* sp = srcs[a]
                + (size_t)((a < 2 ? n0g : m0g) + rb + rowl) * DD + gs * 8;
            ushort* lp = &smem[0][a][rb * 32];
            gload16(sp, lp);
            gload16(sp + 16 * DD, lp + 16 * 32);
        }
        __syncthreads();   // drains vmcnt -> buf0 ready

        int cur = 0;
        for (int c = 0; c < NCH; c++) {
            if (c + 1 < NCH) {                 // prefetch chunk c+1 -> buf^1
                const int k1 = (c + 1) * 32;
#pragma unroll
                for (int a = 0; a < 4; a++) {
                    const ushort* sp = srcs[a]
                        + (size_t)((a < 2 ? n0g : m0g) + rb + rowl) * DD
                        + k1 + gs * 8;
                    ushort* lp = &smem[cur ^ 1][a][rb * 32];
                    gload16(sp, lp);
                    gload16(sp + 16 * DD, lp + 16 * 32);
                }
            }
            bf16x8 ah[4], al[4], bhf[4], blf[4];
#pragma unroll
            for (int i = 0; i < 4; i++) {
                ah[i]  = *(const bf16x8*)&smem[cur][0][ra0 + i * 512];
                al[i]  = *(const bf16x8*)&smem[cur][1][ra0 + i * 512];
                bhf[i] = *(const bf16x8*)&smem[cur][2][rb0 + i * 512];
                blf[i] = *(const bf16x8*)&smem[cur][3][rb0 + i * 512];
            }
#pragma unroll
            for (int i = 0; i < 4; i++)
#pragma unroll
                for (int j = 0; j < 4; j++) {
                    asm("v_mfma_f32_16x16x32_bf16 %0, %1, %2, %0"
                        : "+v"(acc[i][j]) : "v"(ah[i]), "v"(bhf[j]));
                    asm("v_mfma_f32_16x16x32_bf16 %0, %1, %2, %0"
                        : "+v"(acc[i][j]) : "v"(al[i]), "v"(bhf[j]));
                    asm("v_mfma_f32_16x16x32_bf16 %0, %1, %2, %0"
                        : "+v"(acc[i][j]) : "v"(ah[i]), "v"(blf[j]));
                }
            __syncthreads();   // drains vmcnt (c+1 staged) + lgkm; flip
            cur ^= 1;
        }

        // fold this m-tile into running (max, argmax); j ascending + strict >
        // preserves first-occurrence ties (cols ascend with mt and j)
#pragma unroll
        for (int j = 0; j < 4; j++) {
            const int col = m0 + wx * 64 + j * 16 + fr;
#pragma unroll
            for (int i = 0; i < 4; i++)
#pragma unroll
                for (int r = 0; r < 4; r++) {
                    float val = acc[i][j][r];
                    int k = i * 4 + r;
                    if (val > rmax[k]) { rmax[k] = val; ridx[k] = col; }
                }
        }
    }

    // cross-lane reduce over fr (16 lanes share a row set), index tie-break;
    // stage per-wave result in LDS — waves wx=0/1 hold different col halves
    // of the SAME rows and must be merged.
#pragma unroll
    for (int k = 0; k < 16; k++) {
        float m = rmax[k]; int id2 = ridx[k];
#pragma unroll
        for (int off = 1; off < 16; off <<= 1) {
            float om = __shfl_xor(m, off);
            int   oi = __shfl_xor(id2, off);
            if (om > m || (om == m && oi < id2)) { m = om; id2 = oi; }
        }
        if (fr == 0) {
            int r_loc = wy * 64 + (k >> 2) * 16 + fs * 4 + (k & 3);
            redm[wx][r_loc] = m;
            redi[wx][r_loc] = id2;
        }
    }
    __syncthreads();
    if (t < 128) {
        float m0v = redm[0][t]; int i0 = redi[0][t];
        float m1v = redm[1][t]; int i1 = redi[1][t];
        // wx=0 holds lower columns: on exact tie keep smaller index
        if (m1v > m0v || (m1v == m0v && i1 < i0)) { m0v = m1v; i0 = i1; }
        pmax[(b * 4 + ms) * NN + n0 + t] = m0v;
        pidx[(b * 4 + ms) * NN + n0 + t] = i0;
    }
}

// --- Kernel 3: merge 4 m-split partials + sigmoid threshold ----------------
__global__ __launch_bounds__(256) void merge_kernel(
        const float* __restrict__ pmax, const int* __restrict__ pidx,
        const float* __restrict__ st,
        float* __restrict__ out_map,
        float* __restrict__ ws_rm, int* __restrict__ ws_idx) {
    int id = blockIdx.x * 256 + threadIdx.x;   // [0, BN)
    int b = id >> 11, n = id & 2047;
    float best = pmax[(b * 4) * NN + n];
    int   bi   = pidx[(b * 4) * NN + n];
#pragma unroll
    for (int s = 1; s < 4; s++) {
        float p = pmax[(b * 4 + s) * NN + n];
        int   q = pidx[(b * 4 + s) * NN + n];
        if (p > best || (p == best && q < bi)) { best = p; bi = q; }
    }
    float thr = 1.0f / (1.0f + expf(-st[n]));
    float rm  = 1.0f / (1.0f + expf(-40.0f * (best - thr)));
    out_map[id] = rm;
    ws_rm[id]   = rm;
    ws_idx[id]  = bi;
}

// --- Kernel 4: gather + blend, f32 stores (overwrites the bf16 scratch) ----
__global__ __launch_bounds__(256) void blend_kernel(
        const float* __restrict__ qi, const float* __restrict__ qv,
        const float* __restrict__ ci, const float* __restrict__ cv,
        const float* __restrict__ ws_rm, const int* __restrict__ ws_idx,
        float* __restrict__ out_ri, float* __restrict__ out_rv) {
    int row  = blockIdx.x * 4 + (threadIdx.x >> 6);
    int lane = threadIdx.x & 63;
    float rm  = ws_rm[row];
    int gidx  = ws_idx[row];
    int b     = row >> 11;
    float om  = 1.0f - rm;
    const float4* q4 = (const float4*)(qi + (size_t)row * DD);
    const float4* v4 = (const float4*)(qv + (size_t)row * DD);
    const float4* s4 = (const float4*)(ci + ((size_t)b * NN + gidx) * DD);
    const float4* w4 = (const float4*)(cv + ((size_t)b * NN + gidx) * DD);
    float4* ori = (float4*)(out_ri + (size_t)row * DD);
    float4* orv = (float4*)(out_rv + (size_t)row * DD);
#pragma unroll
    for (int k = 0; k < 3; k++) {
        int f = lane + 64 * k;
        float4 a = q4[f], si = s4[f];
        float4 o;
        o.x = om * a.x + rm * si.x;
        o.y = om * a.y + rm * si.y;
        o.z = om * a.z + rm * si.z;
        o.w = om * a.w + rm * si.w;
        ori[f] = o;
        float4 av = v4[f], sv = w4[f];
        float4 p;
        p.x = om * av.x + rm * sv.x;
        p.y = om * av.y + rm * sv.y;
        p.z = om * av.z + rm * sv.z;
        p.w = om * av.w + rm * sv.w;
        orv[f] = p;
    }
}

extern "C" void kernel_launch(void* const* d_in, const int* in_sizes, int n_in,
                              void* d_out, int out_size, void* d_ws, size_t ws_size,
                              hipStream_t stream) {
    const float* qi = (const float*)d_in[0];
    const float* qv = (const float*)d_in[1];
    const float* ci = (const float*)d_in[2];
    const float* cv = (const float*)d_in[3];
    const float* st = (const float*)d_in[4];

    float* ws    = (float*)d_ws;
    float* pmax  = ws;
    int*   pidx  = (int*)(ws + 131072);
    float* ws_rm = ws + 262144;
    int*   ws_id = (int*)(ws + 294912);

    float* out     = (float*)d_out;
    float* out_map = out;                                  // [B,N]
    float* out_ri  = out + 32768;                          // [B,N,D]
    float* out_rv  = out + 32768 + (size_t)BN * DD;        // [B,N,D]

    // bf16 hi/lo scratch aliases the (not-yet-written) big outputs
    ushort* qh = (ushort*)out_ri;
    ushort* ql = qh + (size_t)BN * DD;
    ushort* ch = (ushort*)out_rv;
    ushort* cl = ch + (size_t)BN * DD;

    normconv_kernel<<<(2 * BN) / 4, 256, 0, stream>>>(qi, ci, qh, ql, ch, cl);
    dim3 g2(16, 4, BB);
    simmax_kernel<<<g2, 256, 0, stream>>>(qh, ql, ch, cl, pmax, pidx);
    merge_kernel<<<BN / 256, 256, 0, stream>>>(pmax, pidx, st,
                                               out_map, ws_rm, ws_id);
    blend_kernel<<<BN / 4, 256, 0, stream>>>(qi, qv, ci, cv, ws_rm, ws_id,
                                             out_ri, out_rv);
}